// Round 2
// baseline (121841.931 us; speedup 1.0000x reference)
//
#include <hip/hip_runtime.h>

#define E_   256
#define TE_  512
#define FE_  1024
#define EE_  2048
#define S_   512
#define V_   50257
#define NB_  256
#define NT_  512
#define SOS_ 1

typedef unsigned int u32;
typedef unsigned long long u64;

__device__ __forceinline__ float wsum(float v){
#pragma unroll
  for (int m=1;m<64;m<<=1) v += __shfl_xor(v,m,64);
  return v;
}
__device__ __forceinline__ float wmaxr(float v){
#pragma unroll
  for (int m=1;m<64;m<<=1) v = fmaxf(v,__shfl_xor(v,m,64));
  return v;
}
__device__ __forceinline__ u64 wmax64(u64 v){
#pragma unroll
  for (int m=1;m<64;m<<=1){
    int lo = __shfl_xor((int)(u32)v, m, 64);
    int hi = __shfl_xor((int)(u32)(v>>32), m, 64);
    u64 o = ((u64)(u32)hi<<32)|(u32)lo;
    if (o > v) v = o;
  }
  return v;
}
__device__ __forceinline__ float sigm(float x){ return 1.0f/(1.0f+expf(-x)); }
__device__ __forceinline__ float f4d(float4 a, float4 b){
  return fmaf(a.x,b.x, fmaf(a.y,b.y, fmaf(a.z,b.z, a.w*b.w)));
}

// ---------------- flag-tree grid barrier (no atomic RMW) ----------------
// genArr: 8 copies of the published generation, 128B apart (spread spin load)
// flags : per-block arrival flag, 64B apart, generation-stamped (no reset)
__device__ __forceinline__ void gsyncF(u32* genArr, u32* flags, u32 g, int b){
  __syncthreads();
  if (b == 0) {
    if (threadIdx.x > 0 && threadIdx.x < NB_) {
      u32* f = flags + threadIdx.x*16;
      while (__hip_atomic_load(f, __ATOMIC_ACQUIRE, __HIP_MEMORY_SCOPE_AGENT) < g)
        __builtin_amdgcn_s_sleep(1);
    }
    __syncthreads();
    if (threadIdx.x == 0) __threadfence();
    if (threadIdx.x < 8)
      __hip_atomic_store(genArr + threadIdx.x*32, g, __ATOMIC_RELEASE, __HIP_MEMORY_SCOPE_AGENT);
    __syncthreads();
  } else {
    if (threadIdx.x == 0) {
      __hip_atomic_store(flags + b*16, g, __ATOMIC_RELEASE, __HIP_MEMORY_SCOPE_AGENT);
      while (__hip_atomic_load(genArr + (b&7)*32, __ATOMIC_ACQUIRE, __HIP_MEMORY_SCOPE_AGENT) < g)
        __builtin_amdgcn_s_sleep(1);
      __threadfence();
    }
    __syncthreads();
  }
}
#define GSYNC() do { ++bg; gsyncF(genArr, flags, bg, b); } while(0)

#define FMA8(acc, w0, w1, sh, o) do { \
  acc = fmaf(w0.x, sh[(o)+0], acc); acc = fmaf(w0.y, sh[(o)+1], acc); \
  acc = fmaf(w0.z, sh[(o)+2], acc); acc = fmaf(w0.w, sh[(o)+3], acc); \
  acc = fmaf(w1.x, sh[(o)+4], acc); acc = fmaf(w1.y, sh[(o)+5], acc); \
  acc = fmaf(w1.z, sh[(o)+6], acc); acc = fmaf(w1.w, sh[(o)+7], acc); } while(0)

extern "C" __global__ void __launch_bounds__(NT_, 2)
seq2seq_kernel(const int* __restrict__ tokens,
               const float* __restrict__ enc_emb,
               const float* __restrict__ dec_emb,
               const float* __restrict__ eWi_f, const float* __restrict__ eWh_f, const float* __restrict__ eb_f,
               const float* __restrict__ eWi_b, const float* __restrict__ eWh_b, const float* __restrict__ eb_b,
               const float* __restrict__ dWi, const float* __restrict__ dWh, const float* __restrict__ db,
               const float* __restrict__ attn_W, const float* __restrict__ attn_b,
               const float* __restrict__ W_W, const float* __restrict__ W_b,
               const float* __restrict__ lin_W, const float* __restrict__ lin_b,
               float* __restrict__ out, char* __restrict__ wsb)
{
  const int b = blockIdx.x, tid = threadIdx.x;
  const int wave = tid>>6, lane = tid&63;
  u32 bg = 0;
  u32* genArr = (u32*)wsb;                 // 8 x 128B
  u32* flags  = (u32*)(wsb + 1024);        // 256 x 64B
  u64* argp   = (u64*)(wsb + 17408);       // 256 x 8B
  float* F    = (float*)(wsb + 20480);
  float* emb  = F;                      // S*E
  float* ginF = emb  + S_*E_;           // S*FE
  float* ginB = ginF + S_*FE_;          // S*FE
  float* encM = ginB + S_*FE_;          // [S][TE]
  float* encT = encM + S_*TE_;          // [TE][S]
  float* Mm   = encT + S_*TE_;          // [S][TE]
  float* s0   = Mm   + S_*TE_;          // S
  float* ehid = s0   + S_;              // TE
  float* g0   = ehid + TE_;             // EE
  float* gates= g0   + EE_;             // 2*EE (encoder parity x2 dirs; decoder uses [0,EE))
  float* scor = gates+ 2*EE_;           // S
  float* ctxv = scor + S_;              // TE
  float* yv   = ctxv + TE_;             // FE

  __shared__ float sh_h[TE_], sh_c[TE_], sh_e[TE_], sh_w[TE_], sh_y[FE_];
  __shared__ float sh_red[8];
  __shared__ u64 sh_arg[8];
  __shared__ int sh_word;

  // ================= E0: embed+relu, init h/c =================
  {
    int idx = b*NT_ + tid;                 // 131072 = S*E exactly
    int t = idx >> 8, e = idx & 255;
    float v = enc_emb[(size_t)tokens[t]*E_ + e];
    emb[idx] = v > 0.f ? v : 0.f;
    if (tid < E_) { sh_h[tid]=0.f; sh_c[tid]=0.f; }
  }
  GSYNC();

  // ================= E1: Gin = emb @ Wi.T + b (both dirs) =================
  {
    for (int p = b*4; p < b*4+4; ++p) {    // 1024 (t,dir) pairs
      int d = p >> 9;
      int t = p & 511;
      const float* Wi = d ? eWi_b : eWi_f;
      const float* bb = d ? eb_b  : eb_f;
      float* gin = d ? ginB : ginF;
      if (tid < E_) sh_e[tid] = emb[t*E_ + tid];
      __syncthreads();
      for (int r = wave; r < FE_; r += 8) {
        float4 wv = *(const float4*)(Wi + (size_t)r*E_ + lane*4);
        float acc = wv.x*sh_e[lane*4];
        acc = fmaf(wv.y, sh_e[lane*4+1], acc);
        acc = fmaf(wv.z, sh_e[lane*4+2], acc);
        acc = fmaf(wv.w, sh_e[lane*4+3], acc);
        acc = wsum(acc);
        if (lane==0) gin[(size_t)t*FE_ + r] = acc + bb[r];
      }
      __syncthreads();
    }
  }
  GSYNC();

  // ================= E2: encoder recurrence (1 gsync/step) =================
  {
    const int d  = (b >= 128);
    const int bb = b - d*128;
    const float* Wh  = d ? eWh_b : eWh_f;
    const float* gin = d ? ginB : ginF;
    float* gb = gates + d*2*FE_;           // two parity buffers of FE_ each
    for (int t = 0; t < S_; ++t) {
      if (t > 0) {
        const float* gp = gb + ((t-1)&1)*FE_;
        if (tid < E_) {
          float ig=gp[tid], fg=gp[E_+tid], gg=gp[2*E_+tid], og=gp[3*E_+tid];
          float cc = sigm(fg)*sh_c[tid] + sigm(ig)*tanhf(gg);
          float hh = sigm(og)*tanhf(cc);
          sh_c[tid]=cc; sh_h[tid]=hh;
          if (bb == 0) {
            int row = d ? (S_-1-(t-1)) : (t-1);
            float mv = (tokens[row] > 0) ? hh : 0.f;
            encM[(size_t)row*TE_ + d*E_ + tid] = mv;
            encT[(size_t)(d*E_ + tid)*S_ + row] = mv;
          }
        }
      }
      __syncthreads();
      int ti = d ? (S_-1-t) : t;
      int r = bb*8 + wave;
      float4 wv = *(const float4*)(Wh + (size_t)r*E_ + lane*4);
      float acc = wv.x*sh_h[lane*4];
      acc = fmaf(wv.y, sh_h[lane*4+1], acc);
      acc = fmaf(wv.z, sh_h[lane*4+2], acc);
      acc = fmaf(wv.w, sh_h[lane*4+3], acc);
      acc = wsum(acc);
      if (lane==0) gb[(t&1)*FE_ + r] = gin[(size_t)ti*FE_ + r] + acc;
      GSYNC();
    }
    // final h + last encoded rows + enc_hidden
    {
      const float* gp = gb + ((S_-1)&1)*FE_;
      if (tid < E_) {
        float ig=gp[tid], fg=gp[E_+tid], gg=gp[2*E_+tid], og=gp[3*E_+tid];
        float cc = sigm(fg)*sh_c[tid] + sigm(ig)*tanhf(gg);
        float hh = sigm(og)*tanhf(cc);
        if (bb == 0) {
          int row = d ? 0 : (S_-1);
          float mv = (tokens[row] > 0) ? hh : 0.f;
          encM[(size_t)row*TE_ + d*E_ + tid] = mv;
          encT[(size_t)(d*E_ + tid)*S_ + row] = mv;
          ehid[d*E_ + tid] = hh;
        }
      }
    }
  }
  GSYNC();

  // ================= A1: M = encM@attn_W, s0, g0, decoder init =================
  {
    int t0 = b*2, t1 = b*2+1;
    sh_e[tid] = encM[(size_t)t0*TE_ + tid];
    sh_w[tid] = encM[(size_t)t1*TE_ + tid];
    __syncthreads();
    float a0=0.f, a1=0.f;
    for (int j = 0; j < TE_; ++j) {
      float wv = attn_W[(size_t)j*TE_ + tid];
      a0 = fmaf(sh_e[j], wv, a0);
      a1 = fmaf(sh_w[j], wv, a1);
    }
    Mm[(size_t)t0*TE_ + tid] = a0;
    Mm[(size_t)t1*TE_ + tid] = a1;
    // s0[t] = encM[t] . attn_b
    float p0 = sh_e[tid]*attn_b[tid];
    float p1 = sh_w[tid]*attn_b[tid];
    p0 = wsum(p0); p1 = wsum(p1);
    if (lane==0) sh_red[wave] = p0;
    __syncthreads();
    if (tid==0){ float s=0.f; for(int w=0;w<8;++w) s+=sh_red[w]; s0[t0]=s; }
    __syncthreads();
    if (lane==0) sh_red[wave] = p1;
    __syncthreads();
    if (tid==0){ float s=0.f; for(int w=0;w<8;++w) s+=sh_red[w]; s0[t1]=s; }
    // g0[r] = dWi[r,512:]@enc_hidden + db[r]
    {
      int r = b*8 + wave;
      const int o = lane*8;
      float4 w0 = *(const float4*)(dWi + (size_t)r*FE_ + TE_ + o);
      float4 w1 = *(const float4*)(dWi + (size_t)r*FE_ + TE_ + o + 4);
      float acc = 0.f;
      acc = fmaf(w0.x, ehid[o+0], acc); acc = fmaf(w0.y, ehid[o+1], acc);
      acc = fmaf(w0.z, ehid[o+2], acc); acc = fmaf(w0.w, ehid[o+3], acc);
      acc = fmaf(w1.x, ehid[o+4], acc); acc = fmaf(w1.y, ehid[o+5], acc);
      acc = fmaf(w1.z, ehid[o+6], acc); acc = fmaf(w1.w, ehid[o+7], acc);
      acc = wsum(acc);
      if (lane==0) g0[r] = acc + db[r];
    }
    __syncthreads();
    // decoder state init
    sh_h[tid] = ehid[tid];
    sh_c[tid] = 0.f;
    if (tid==0) sh_word = SOS_;
    if (b==0 && tid==0) out[0] = (float)SOS_;
  }
  GSYNC();

  // ================= D: decode loop (5 gsyncs/step) =================
  const int rb = b*196 + (b < 81 ? b : 81);
  const int nr = 196 + (b < 81 ? 1 : 0);
  for (int t = 0; t < S_; ++t) {
    // ---- P1: finalize argmax of step t-1; embed; gates ----
    if (t > 0) {
      if (tid < NB_) {
        u64 v = argp[tid];
        v = wmax64(v);
        if (lane==0) sh_arg[wave] = v;       // waves 0..3
      }
      __syncthreads();
      if (tid==0) {
        u64 best = sh_arg[0];
        for (int w=1;w<4;++w) if (sh_arg[w]>best) best = sh_arg[w];
        int wd = (int)(0xFFFFFFFFu - (u32)best);
        sh_word = wd;
        if (b==0) out[t] = (float)wd;        // sentence[1+(t-1)]
      }
      __syncthreads();
    }
    {
      int word = sh_word;
      float v = dec_emb[(size_t)word*TE_ + tid];
      sh_e[tid] = v > 0.f ? v : 0.f;
    }
    __syncthreads();
    {
      int r = b*8 + wave;
      const float* wi = dWi + (size_t)r*FE_;
      const float* wh = dWh + (size_t)r*TE_;
      const int o = lane*8;
      float4 a0 = *(const float4*)(wi + o);
      float4 a1 = *(const float4*)(wi + o + 4);
      float4 b0 = *(const float4*)(wh + o);
      float4 b1 = *(const float4*)(wh + o + 4);
      float acc = 0.f;
      FMA8(acc, a0, a1, sh_e, o);
      FMA8(acc, b0, b1, sh_h, o);
      acc = wsum(acc);
      if (lane==0) gates[r] = acc + g0[r];
    }
    GSYNC();
    // ---- P2: h,c update (redundant); scores ----
    {
      float ig=gates[tid], fg=gates[TE_+tid], gg=gates[2*TE_+tid], og=gates[3*TE_+tid];
      float cc = sigm(fg)*sh_c[tid] + sigm(ig)*tanhf(gg);
      float hh = sigm(og)*tanhf(cc);
      sh_c[tid]=cc; sh_h[tid]=hh;
    }
    __syncthreads();
    if (wave < 2) {
      int r = b*2 + wave;
      const float* mr = Mm + (size_t)r*TE_;
      const int o = lane*8;
      float4 m0 = *(const float4*)(mr + o);
      float4 m1 = *(const float4*)(mr + o + 4);
      float acc = 0.f;
      FMA8(acc, m0, m1, sh_h, o);
      acc = wsum(acc);
      if (lane==0) scor[r] = acc + s0[r];
    }
    GSYNC();
    // ---- P3: softmax (redundant); context ----
    {
      bool msk = tokens[tid] > 0;
      float s = msk ? scor[tid] : -__builtin_inff();
      float mx = wmaxr(s);
      if (lane==0) sh_red[wave] = mx;
      __syncthreads();
      float m2 = sh_red[0];
      for (int w=1;w<8;++w) m2 = fmaxf(m2, sh_red[w]);
      float ev = (s == -__builtin_inff()) ? 0.f : expf(s - m2);
      float sm = wsum(ev);
      __syncthreads();
      if (lane==0) sh_red[wave] = sm;
      __syncthreads();
      float tot = 0.f;
      for (int w=0;w<8;++w) tot += sh_red[w];
      sh_w[tid] = (tot > 0.f) ? ev/tot : 0.f;
    }
    __syncthreads();
    if (wave < 2) {
      int j = b*2 + wave;
      const float* er = encT + (size_t)j*S_;
      const int o = lane*8;
      float4 e0 = *(const float4*)(er + o);
      float4 e1 = *(const float4*)(er + o + 4);
      float acc = 0.f;
      FMA8(acc, e0, e1, sh_w, o);
      acc = wsum(acc);
      if (lane==0) ctxv[j] = acc;
    }
    GSYNC();
    // ---- P4: y = W_W @ [h;ctx] + W_b ----
    sh_e[tid] = ctxv[tid];
    __syncthreads();
    if (wave < 4) {
      int r = b*4 + wave;
      const float* wr = W_W + (size_t)r*FE_;
      const int o = lane*8;
      float4 a0 = *(const float4*)(wr + o);
      float4 a1 = *(const float4*)(wr + o + 4);
      float4 c0 = *(const float4*)(wr + TE_ + o);
      float4 c1 = *(const float4*)(wr + TE_ + o + 4);
      float acc = 0.f;
      FMA8(acc, a0, a1, sh_h, o);
      FMA8(acc, c0, c1, sh_e, o);
      acc = wsum(acc);
      if (lane==0) yv[r] = acc + W_b[r];
    }
    GSYNC();
    // ---- P5: logits = lin_W @ y + lin_b; 4-row batched GEMV; partial argmax ----
    sh_y[tid]      = yv[tid];
    sh_y[tid+NT_]  = yv[tid+NT_];
    __syncthreads();
    {
      const int o = lane*4;
      const float4 yv0 = *(const float4*)(sh_y + o);
      const float4 yv1 = *(const float4*)(sh_y + 256 + o);
      const float4 yv2 = *(const float4*)(sh_y + 512 + o);
      const float4 yv3 = *(const float4*)(sh_y + 768 + o);
      u64 best = 0;
      float* outrow = out + 513 + (size_t)t*V_;
      const int sRow = (nr*wave)>>3, eRow = (nr*(wave+1))>>3;
      for (int i = sRow; i < eRow; i += 4) {
        const int r0 = rb + i;
        const int k1 = (i+1<eRow)?1:0, k2 = (i+2<eRow)?2:0, k3 = (i+3<eRow)?3:0;
        const float* p0 = lin_W + (size_t)r0*FE_ + o;
        const float* p1 = lin_W + (size_t)(r0+k1)*FE_ + o;
        const float* p2 = lin_W + (size_t)(r0+k2)*FE_ + o;
        const float* p3 = lin_W + (size_t)(r0+k3)*FE_ + o;
        float4 a0=*(const float4*)(p0),     a1=*(const float4*)(p0+256), a2=*(const float4*)(p0+512), a3=*(const float4*)(p0+768);
        float4 b0=*(const float4*)(p1),     b1=*(const float4*)(p1+256), b2=*(const float4*)(p1+512), b3=*(const float4*)(p1+768);
        float4 c0=*(const float4*)(p2),     c1=*(const float4*)(p2+256), c2=*(const float4*)(p2+512), c3=*(const float4*)(p2+768);
        float4 d0=*(const float4*)(p3),     d1=*(const float4*)(p3+256), d2=*(const float4*)(p3+512), d3=*(const float4*)(p3+768);
        float acc0 = f4d(a0,yv0)+f4d(a1,yv1)+f4d(a2,yv2)+f4d(a3,yv3);
        float acc1 = f4d(b0,yv0)+f4d(b1,yv1)+f4d(b2,yv2)+f4d(b3,yv3);
        float acc2 = f4d(c0,yv0)+f4d(c1,yv1)+f4d(c2,yv2)+f4d(c3,yv3);
        float acc3 = f4d(d0,yv0)+f4d(d1,yv1)+f4d(d2,yv2)+f4d(d3,yv3);
        acc0 = wsum(acc0); acc1 = wsum(acc1); acc2 = wsum(acc2); acc3 = wsum(acc3);
        if (lane==0) {
          float lg = acc0 + lin_b[r0];
          __builtin_nontemporal_store(lg, outrow + r0);
          u32 u = __float_as_uint(lg);
          u = u ^ ((u32)((int)u>>31) | 0x80000000u);
          u64 pk = ((u64)u<<32) | (u64)(0xFFFFFFFFu - (u32)r0);
          if (pk > best) best = pk;
          if (k1) {
            lg = acc1 + lin_b[r0+1];
            __builtin_nontemporal_store(lg, outrow + r0+1);
            u = __float_as_uint(lg); u = u ^ ((u32)((int)u>>31) | 0x80000000u);
            pk = ((u64)u<<32) | (u64)(0xFFFFFFFFu - (u32)(r0+1));
            if (pk > best) best = pk;
          }
          if (k2) {
            lg = acc2 + lin_b[r0+2];
            __builtin_nontemporal_store(lg, outrow + r0+2);
            u = __float_as_uint(lg); u = u ^ ((u32)((int)u>>31) | 0x80000000u);
            pk = ((u64)u<<32) | (u64)(0xFFFFFFFFu - (u32)(r0+2));
            if (pk > best) best = pk;
          }
          if (k3) {
            lg = acc3 + lin_b[r0+3];
            __builtin_nontemporal_store(lg, outrow + r0+3);
            u = __float_as_uint(lg); u = u ^ ((u32)((int)u>>31) | 0x80000000u);
            pk = ((u64)u<<32) | (u64)(0xFFFFFFFFu - (u32)(r0+3));
            if (pk > best) best = pk;
          }
        }
      }
      if (lane==0) sh_arg[wave] = best;
      __syncthreads();
      if (tid==0){
        u64 bb2 = sh_arg[0];
        for (int w=1;w<8;++w) if (sh_arg[w] > bb2) bb2 = sh_arg[w];
        argp[b] = bb2;
      }
    }
    GSYNC();
  }
  // ================= final word =================
  if (b==0) {
    if (tid < NB_) {
      u64 v = argp[tid];
      v = wmax64(v);
      if (lane==0) sh_arg[wave] = v;
    }
    __syncthreads();
    if (tid==0){
      u64 best = sh_arg[0];
      for (int w=1;w<4;++w) if (sh_arg[w]>best) best = sh_arg[w];
      out[S_] = (float)(0xFFFFFFFFu - (u32)best);
    }
  }
}

extern "C" void kernel_launch(void* const* d_in, const int* in_sizes, int n_in,
                              void* d_out, int out_size, void* d_ws, size_t ws_size,
                              hipStream_t stream) {
  (void)in_sizes; (void)n_in; (void)out_size; (void)ws_size;
  hipMemsetAsync(d_ws, 0, 20480, stream);   // genArr + flags (generation-stamped)
  hipLaunchKernelGGL(seq2seq_kernel, dim3(NB_), dim3(NT_), 0, stream,
    (const int*)  d_in[0],
    (const float*)d_in[2],  (const float*)d_in[3],
    (const float*)d_in[4],  (const float*)d_in[5],  (const float*)d_in[6],
    (const float*)d_in[7],  (const float*)d_in[8],  (const float*)d_in[9],
    (const float*)d_in[10], (const float*)d_in[11], (const float*)d_in[12],
    (const float*)d_in[13], (const float*)d_in[14],
    (const float*)d_in[15], (const float*)d_in[16],
    (const float*)d_in[17], (const float*)d_in[18],
    (float*)d_out, (char*)d_ws);
}

// Round 3
// 24131.953 us; speedup vs baseline: 5.0490x; 5.0490x over previous
//
#include <hip/hip_runtime.h>

#define E_   256
#define TE_  512
#define FE_  1024
#define EE_  2048
#define S_   512
#define V_   50257
#define NB_  256
#define NT_  512
#define SOS_ 1

typedef unsigned int u32;
typedef unsigned long long u64;

// ---------- relaxed agent-scope (cache-bypassing, fence-free) accessors ----------
__device__ __forceinline__ u32 ldA(const u32* p){
  return __hip_atomic_load((u32*)p, __ATOMIC_RELAXED, __HIP_MEMORY_SCOPE_AGENT);
}
__device__ __forceinline__ void stA(u32* p, u32 v){
  __hip_atomic_store(p, v, __ATOMIC_RELAXED, __HIP_MEMORY_SCOPE_AGENT);
}
__device__ __forceinline__ float ldAf(const float* p){
  return __hip_atomic_load((float*)p, __ATOMIC_RELAXED, __HIP_MEMORY_SCOPE_AGENT);
}
__device__ __forceinline__ void stAf(float* p, float v){
  __hip_atomic_store(p, v, __ATOMIC_RELAXED, __HIP_MEMORY_SCOPE_AGENT);
}
__device__ __forceinline__ u64 ldA8(const u64* p){
  return __hip_atomic_load((u64*)p, __ATOMIC_RELAXED, __HIP_MEMORY_SCOPE_AGENT);
}
__device__ __forceinline__ void stA8(u64* p, u64 v){
  __hip_atomic_store(p, v, __ATOMIC_RELAXED, __HIP_MEMORY_SCOPE_AGENT);
}

__device__ __forceinline__ float wsum(float v){
#pragma unroll
  for (int m=1;m<64;m<<=1) v += __shfl_xor(v,m,64);
  return v;
}
__device__ __forceinline__ float wmaxr(float v){
#pragma unroll
  for (int m=1;m<64;m<<=1) v = fmaxf(v,__shfl_xor(v,m,64));
  return v;
}
__device__ __forceinline__ u64 wmax64(u64 v){
#pragma unroll
  for (int m=1;m<64;m<<=1){
    int lo = __shfl_xor((int)(u32)v, m, 64);
    int hi = __shfl_xor((int)(u32)(v>>32), m, 64);
    u64 o = ((u64)(u32)hi<<32)|(u32)lo;
    if (o > v) v = o;
  }
  return v;
}
__device__ __forceinline__ float sigm(float x){ return 1.0f/(1.0f+expf(-x)); }
__device__ __forceinline__ float f4d(float4 a, float4 b){
  return fmaf(a.x,b.x, fmaf(a.y,b.y, fmaf(a.z,b.z, a.w*b.w)));
}

// ---------------- fence-free grid barrier ----------------
// Correctness: __syncthreads() at entry drains each wave's vmcnt(0) (compiler-
// enforced), so every bypass store of this block is at the coherence point
// before thread0 publishes its flag. Block 0 observes all flags, publishes the
// generation to 8 spread lines; spinners observe it with bypass loads. No
// buffer_inv / buffer_wbl2 anywhere -> cached weights stay resident.
__device__ __forceinline__ void gsyncL(u32* genArr, u32* flags, u32 g, int b){
  __syncthreads();
  if (b == 0) {
    if (threadIdx.x > 0 && threadIdx.x < NB_) {
      u32* f = flags + threadIdx.x*16;
      while (ldA(f) < g) __builtin_amdgcn_s_sleep(2);
    }
    __syncthreads();
    if (threadIdx.x < 8) stA(genArr + threadIdx.x*32, g);
  } else {
    if (threadIdx.x == 0) {
      stA(flags + b*16, g);
      while (ldA(genArr + (b&7)*32) < g) __builtin_amdgcn_s_sleep(2);
    }
  }
  __syncthreads();
}
#define GSYNC() do { ++bg; gsyncL(genArr, flags, bg, b); } while(0)

#define FMA8(acc, w0, w1, sh, o) do { \
  acc = fmaf(w0.x, sh[(o)+0], acc); acc = fmaf(w0.y, sh[(o)+1], acc); \
  acc = fmaf(w0.z, sh[(o)+2], acc); acc = fmaf(w0.w, sh[(o)+3], acc); \
  acc = fmaf(w1.x, sh[(o)+4], acc); acc = fmaf(w1.y, sh[(o)+5], acc); \
  acc = fmaf(w1.z, sh[(o)+6], acc); acc = fmaf(w1.w, sh[(o)+7], acc); } while(0)

extern "C" __global__ void __launch_bounds__(NT_, 2)
seq2seq_kernel(const int* __restrict__ tokens,
               const float* __restrict__ enc_emb,
               const float* __restrict__ dec_emb,
               const float* __restrict__ eWi_f, const float* __restrict__ eWh_f, const float* __restrict__ eb_f,
               const float* __restrict__ eWi_b, const float* __restrict__ eWh_b, const float* __restrict__ eb_b,
               const float* __restrict__ dWi, const float* __restrict__ dWh, const float* __restrict__ db,
               const float* __restrict__ attn_W, const float* __restrict__ attn_b,
               const float* __restrict__ W_W, const float* __restrict__ W_b,
               const float* __restrict__ lin_W, const float* __restrict__ lin_b,
               float* __restrict__ out, char* __restrict__ wsb)
{
  const int b = blockIdx.x, tid = threadIdx.x;
  const int wave = tid>>6, lane = tid&63;
  u32 bg = 0;
  u32* genArr = (u32*)wsb;                 // 8 x 128B
  u32* flags  = (u32*)(wsb + 1024);        // 256 x 64B
  u64* argp   = (u64*)(wsb + 17408);       // 256 x 8B
  float* F    = (float*)(wsb + 20480);
  float* emb  = F;                      // S*E       (bypass)
  float* ginF = emb  + S_*E_;           // S*FE      (bypass)
  float* ginB = ginF + S_*FE_;          // S*FE      (bypass)
  float* encM = ginB + S_*FE_;          // [S][TE]   (bypass write, cached read after settle)
  float* encT = encM + S_*TE_;          // [TE][S]   (bypass write, cached read after settle)
  float* Mm   = encT + S_*TE_;          // [S][TE]   (same-block: cached)
  float* s0   = Mm   + S_*TE_;          // S         (same-block: cached)
  float* ehid = s0   + S_;              // TE        (bypass write, cached first-touch read)
  float* g0   = ehid + TE_;             // EE        (same-block: cached)
  float* gates= g0   + EE_;             // 2*EE      (bypass)
  float* scor = gates+ 2*EE_;           // S         (bypass)
  float* ctxv = scor + S_;              // TE        (bypass)
  float* yv   = ctxv + TE_;             // FE        (bypass)

  __shared__ float sh_h[TE_], sh_c[TE_], sh_e[TE_], sh_w[TE_], sh_y[FE_];
  __shared__ float sh_red[8];
  __shared__ u64 sh_arg[8];
  __shared__ int sh_word;

  // ================= E0: embed+relu, init h/c =================
  {
    int idx = b*NT_ + tid;                 // 131072 = S*E exactly
    int t = idx >> 8, e = idx & 255;
    float v = enc_emb[(size_t)tokens[t]*E_ + e];
    stAf(emb + idx, v > 0.f ? v : 0.f);
    if (tid < E_) { sh_h[tid]=0.f; sh_c[tid]=0.f; }
  }
  GSYNC();

  // ================= E1: Gin = emb @ Wi.T + b (both dirs) =================
  {
    for (int p = b*4; p < b*4+4; ++p) {    // 1024 (t,dir) pairs
      int d = p >> 9;
      int t = p & 511;
      const float* Wi = d ? eWi_b : eWi_f;
      const float* bb = d ? eb_b  : eb_f;
      float* gin = d ? ginB : ginF;
      if (tid < E_) sh_e[tid] = ldAf(emb + t*E_ + tid);
      __syncthreads();
      for (int r = wave; r < FE_; r += 8) {
        float4 wv = *(const float4*)(Wi + (size_t)r*E_ + lane*4);
        float acc = wv.x*sh_e[lane*4];
        acc = fmaf(wv.y, sh_e[lane*4+1], acc);
        acc = fmaf(wv.z, sh_e[lane*4+2], acc);
        acc = fmaf(wv.w, sh_e[lane*4+3], acc);
        acc = wsum(acc);
        if (lane==0) stAf(gin + (size_t)t*FE_ + r, acc + bb[r]);
      }
      __syncthreads();
    }
  }
  GSYNC();

  // ================= E2: encoder recurrence (1 gsync/step) =================
  {
    const int d  = (b >= 128);
    const int bb = b - d*128;
    const float* Wh  = d ? eWh_b : eWh_f;
    const float* gin = d ? ginB : ginF;
    float* gb = gates + d*2*FE_;           // two parity buffers of FE_ each
    for (int t = 0; t < S_; ++t) {
      if (t > 0) {
        const float* gp = gb + ((t-1)&1)*FE_;
        if (tid < E_) {
          float ig=ldAf(gp+tid), fg=ldAf(gp+E_+tid), gg=ldAf(gp+2*E_+tid), og=ldAf(gp+3*E_+tid);
          float cc = sigm(fg)*sh_c[tid] + sigm(ig)*tanhf(gg);
          float hh = sigm(og)*tanhf(cc);
          sh_c[tid]=cc; sh_h[tid]=hh;
          if (bb == 0) {
            int row = d ? (S_-1-(t-1)) : (t-1);
            float mv = (tokens[row] > 0) ? hh : 0.f;
            stAf(encM + (size_t)row*TE_ + d*E_ + tid, mv);
            stAf(encT + (size_t)(d*E_ + tid)*S_ + row, mv);
          }
        }
      }
      __syncthreads();
      int ti = d ? (S_-1-t) : t;
      int r = bb*8 + wave;
      float4 wv = *(const float4*)(Wh + (size_t)r*E_ + lane*4);
      float acc = wv.x*sh_h[lane*4];
      acc = fmaf(wv.y, sh_h[lane*4+1], acc);
      acc = fmaf(wv.z, sh_h[lane*4+2], acc);
      acc = fmaf(wv.w, sh_h[lane*4+3], acc);
      acc = wsum(acc);
      if (lane==0) stAf(gb + (t&1)*FE_ + r, ldAf(gin + (size_t)ti*FE_ + r) + acc);
      GSYNC();
    }
    // final h + last encoded rows + enc_hidden
    {
      const float* gp = gb + ((S_-1)&1)*FE_;
      if (tid < E_) {
        float ig=ldAf(gp+tid), fg=ldAf(gp+E_+tid), gg=ldAf(gp+2*E_+tid), og=ldAf(gp+3*E_+tid);
        float cc = sigm(fg)*sh_c[tid] + sigm(ig)*tanhf(gg);
        float hh = sigm(og)*tanhf(cc);
        if (bb == 0) {
          int row = d ? 0 : (S_-1);
          float mv = (tokens[row] > 0) ? hh : 0.f;
          stAf(encM + (size_t)row*TE_ + d*E_ + tid, mv);
          stAf(encT + (size_t)(d*E_ + tid)*S_ + row, mv);
          stAf(ehid + d*E_ + tid, hh);
        }
      }
    }
  }
  GSYNC();

  // ================= A1: M = encM@attn_W, s0, g0, decoder init =================
  // encM/ehid were bypass-written and are first-touched here -> cached reads safe.
  {
    int t0 = b*2, t1 = b*2+1;
    sh_e[tid] = encM[(size_t)t0*TE_ + tid];
    sh_w[tid] = encM[(size_t)t1*TE_ + tid];
    __syncthreads();
    float a0=0.f, a1=0.f;
    for (int j = 0; j < TE_; ++j) {
      float wv = attn_W[(size_t)j*TE_ + tid];
      a0 = fmaf(sh_e[j], wv, a0);
      a1 = fmaf(sh_w[j], wv, a1);
    }
    Mm[(size_t)t0*TE_ + tid] = a0;       // same-block reuse: cached
    Mm[(size_t)t1*TE_ + tid] = a1;
    // s0[t] = encM[t] . attn_b
    float p0 = sh_e[tid]*attn_b[tid];
    float p1 = sh_w[tid]*attn_b[tid];
    p0 = wsum(p0); p1 = wsum(p1);
    if (lane==0) sh_red[wave] = p0;
    __syncthreads();
    if (tid==0){ float s=0.f; for(int w=0;w<8;++w) s+=sh_red[w]; s0[t0]=s; }
    __syncthreads();
    if (lane==0) sh_red[wave] = p1;
    __syncthreads();
    if (tid==0){ float s=0.f; for(int w=0;w<8;++w) s+=sh_red[w]; s0[t1]=s; }
    // g0[r] = dWi[r,512:]@enc_hidden + db[r]
    {
      int r = b*8 + wave;
      const int o = lane*8;
      float4 w0 = *(const float4*)(dWi + (size_t)r*FE_ + TE_ + o);
      float4 w1 = *(const float4*)(dWi + (size_t)r*FE_ + TE_ + o + 4);
      float acc = 0.f;
      acc = fmaf(w0.x, ehid[o+0], acc); acc = fmaf(w0.y, ehid[o+1], acc);
      acc = fmaf(w0.z, ehid[o+2], acc); acc = fmaf(w0.w, ehid[o+3], acc);
      acc = fmaf(w1.x, ehid[o+4], acc); acc = fmaf(w1.y, ehid[o+5], acc);
      acc = fmaf(w1.z, ehid[o+6], acc); acc = fmaf(w1.w, ehid[o+7], acc);
      acc = wsum(acc);
      if (lane==0) g0[r] = acc + db[r];  // same-block reuse: cached
    }
    __syncthreads();
    // decoder state init
    sh_h[tid] = ehid[tid];
    sh_c[tid] = 0.f;
    if (tid==0) sh_word = SOS_;
    if (b==0 && tid==0) out[0] = (float)SOS_;
  }
  GSYNC();

  // ================= D: decode loop (5 gsyncs/step) =================
  const int rb = b*196 + (b < 81 ? b : 81);
  const int nr = 196 + (b < 81 ? 1 : 0);
  for (int t = 0; t < S_; ++t) {
    // ---- P1: finalize argmax of step t-1; embed; gates ----
    if (t > 0) {
      if (tid < NB_) {
        u64 v = ldA8(argp + tid);
        v = wmax64(v);
        if (lane==0) sh_arg[wave] = v;       // waves 0..3
      }
      __syncthreads();
      if (tid==0) {
        u64 best = sh_arg[0];
        for (int w=1;w<4;++w) if (sh_arg[w]>best) best = sh_arg[w];
        int wd = (int)(0xFFFFFFFFu - (u32)best);
        sh_word = wd;
        if (b==0) out[t] = (float)wd;        // sentence[1+(t-1)]
      }
      __syncthreads();
    }
    {
      int word = sh_word;
      float v = dec_emb[(size_t)word*TE_ + tid];
      sh_e[tid] = v > 0.f ? v : 0.f;
    }
    __syncthreads();
    {
      int r = b*8 + wave;
      const float* wi = dWi + (size_t)r*FE_;
      const float* wh = dWh + (size_t)r*TE_;
      const int o = lane*8;
      float4 a0 = *(const float4*)(wi + o);
      float4 a1 = *(const float4*)(wi + o + 4);
      float4 b0 = *(const float4*)(wh + o);
      float4 b1 = *(const float4*)(wh + o + 4);
      float acc = 0.f;
      FMA8(acc, a0, a1, sh_e, o);
      FMA8(acc, b0, b1, sh_h, o);
      acc = wsum(acc);
      if (lane==0) stAf(gates + r, acc + g0[r]);
    }
    GSYNC();
    // ---- P2: h,c update (redundant); scores ----
    {
      float ig=ldAf(gates+tid), fg=ldAf(gates+TE_+tid),
            gg=ldAf(gates+2*TE_+tid), og=ldAf(gates+3*TE_+tid);
      float cc = sigm(fg)*sh_c[tid] + sigm(ig)*tanhf(gg);
      float hh = sigm(og)*tanhf(cc);
      sh_c[tid]=cc; sh_h[tid]=hh;
    }
    __syncthreads();
    if (wave < 2) {
      int r = b*2 + wave;
      const float* mr = Mm + (size_t)r*TE_;
      const int o = lane*8;
      float4 m0 = *(const float4*)(mr + o);
      float4 m1 = *(const float4*)(mr + o + 4);
      float acc = 0.f;
      FMA8(acc, m0, m1, sh_h, o);
      acc = wsum(acc);
      if (lane==0) stAf(scor + r, acc + s0[r]);
    }
    GSYNC();
    // ---- P3: softmax (redundant); context ----
    {
      bool msk = tokens[tid] > 0;
      float s = msk ? ldAf(scor + tid) : -__builtin_inff();
      float mx = wmaxr(s);
      if (lane==0) sh_red[wave] = mx;
      __syncthreads();
      float m2 = sh_red[0];
      for (int w=1;w<8;++w) m2 = fmaxf(m2, sh_red[w]);
      float ev = (s == -__builtin_inff()) ? 0.f : expf(s - m2);
      float sm = wsum(ev);
      __syncthreads();
      if (lane==0) sh_red[wave] = sm;
      __syncthreads();
      float tot = 0.f;
      for (int w=0;w<8;++w) tot += sh_red[w];
      sh_w[tid] = (tot > 0.f) ? ev/tot : 0.f;
    }
    __syncthreads();
    if (wave < 2) {
      int j = b*2 + wave;
      const float* er = encT + (size_t)j*S_;     // read-only after E2: cached
      const int o = lane*8;
      float4 e0 = *(const float4*)(er + o);
      float4 e1 = *(const float4*)(er + o + 4);
      float acc = 0.f;
      FMA8(acc, e0, e1, sh_w, o);
      acc = wsum(acc);
      if (lane==0) stAf(ctxv + j, acc);
    }
    GSYNC();
    // ---- P4: y = W_W @ [h;ctx] + W_b ----
    sh_e[tid] = ldAf(ctxv + tid);
    __syncthreads();
    if (wave < 4) {
      int r = b*4 + wave;
      const float* wr = W_W + (size_t)r*FE_;
      const int o = lane*8;
      float4 a0 = *(const float4*)(wr + o);
      float4 a1 = *(const float4*)(wr + o + 4);
      float4 c0 = *(const float4*)(wr + TE_ + o);
      float4 c1 = *(const float4*)(wr + TE_ + o + 4);
      float acc = 0.f;
      FMA8(acc, a0, a1, sh_h, o);
      FMA8(acc, c0, c1, sh_e, o);
      acc = wsum(acc);
      if (lane==0) stAf(yv + r, acc + W_b[r]);
    }
    GSYNC();
    // ---- P5: logits = lin_W @ y + lin_b; 4-row batched GEMV; partial argmax ----
    sh_y[tid]      = ldAf(yv + tid);
    sh_y[tid+NT_]  = ldAf(yv + tid + NT_);
    __syncthreads();
    {
      const int o = lane*4;
      const float4 yv0 = *(const float4*)(sh_y + o);
      const float4 yv1 = *(const float4*)(sh_y + 256 + o);
      const float4 yv2 = *(const float4*)(sh_y + 512 + o);
      const float4 yv3 = *(const float4*)(sh_y + 768 + o);
      u64 best = 0;
      float* outrow = out + 513 + (size_t)t*V_;
      const int sRow = (nr*wave)>>3, eRow = (nr*(wave+1))>>3;
      for (int i = sRow; i < eRow; i += 4) {
        const int r0 = rb + i;
        const int k1 = (i+1<eRow)?1:0, k2 = (i+2<eRow)?2:0, k3 = (i+3<eRow)?3:0;
        const float* p0 = lin_W + (size_t)r0*FE_ + o;
        const float* p1 = lin_W + (size_t)(r0+k1)*FE_ + o;
        const float* p2 = lin_W + (size_t)(r0+k2)*FE_ + o;
        const float* p3 = lin_W + (size_t)(r0+k3)*FE_ + o;
        float4 a0=*(const float4*)(p0),     a1=*(const float4*)(p0+256), a2=*(const float4*)(p0+512), a3=*(const float4*)(p0+768);
        float4 b0=*(const float4*)(p1),     b1=*(const float4*)(p1+256), b2=*(const float4*)(p1+512), b3=*(const float4*)(p1+768);
        float4 c0=*(const float4*)(p2),     c1=*(const float4*)(p2+256), c2=*(const float4*)(p2+512), c3=*(const float4*)(p2+768);
        float4 d0=*(const float4*)(p3),     d1=*(const float4*)(p3+256), d2=*(const float4*)(p3+512), d3=*(const float4*)(p3+768);
        float acc0 = f4d(a0,yv0)+f4d(a1,yv1)+f4d(a2,yv2)+f4d(a3,yv3);
        float acc1 = f4d(b0,yv0)+f4d(b1,yv1)+f4d(b2,yv2)+f4d(b3,yv3);
        float acc2 = f4d(c0,yv0)+f4d(c1,yv1)+f4d(c2,yv2)+f4d(c3,yv3);
        float acc3 = f4d(d0,yv0)+f4d(d1,yv1)+f4d(d2,yv2)+f4d(d3,yv3);
        acc0 = wsum(acc0); acc1 = wsum(acc1); acc2 = wsum(acc2); acc3 = wsum(acc3);
        if (lane==0) {
          float lg = acc0 + lin_b[r0];
          __builtin_nontemporal_store(lg, outrow + r0);
          u32 u = __float_as_uint(lg);
          u = u ^ ((u32)((int)u>>31) | 0x80000000u);
          u64 pk = ((u64)u<<32) | (u64)(0xFFFFFFFFu - (u32)r0);
          if (pk > best) best = pk;
          if (k1) {
            lg = acc1 + lin_b[r0+1];
            __builtin_nontemporal_store(lg, outrow + r0+1);
            u = __float_as_uint(lg); u = u ^ ((u32)((int)u>>31) | 0x80000000u);
            pk = ((u64)u<<32) | (u64)(0xFFFFFFFFu - (u32)(r0+1));
            if (pk > best) best = pk;
          }
          if (k2) {
            lg = acc2 + lin_b[r0+2];
            __builtin_nontemporal_store(lg, outrow + r0+2);
            u = __float_as_uint(lg); u = u ^ ((u32)((int)u>>31) | 0x80000000u);
            pk = ((u64)u<<32) | (u64)(0xFFFFFFFFu - (u32)(r0+2));
            if (pk > best) best = pk;
          }
          if (k3) {
            lg = acc3 + lin_b[r0+3];
            __builtin_nontemporal_store(lg, outrow + r0+3);
            u = __float_as_uint(lg); u = u ^ ((u32)((int)u>>31) | 0x80000000u);
            pk = ((u64)u<<32) | (u64)(0xFFFFFFFFu - (u32)(r0+3));
            if (pk > best) best = pk;
          }
        }
      }
      if (lane==0) sh_arg[wave] = best;
      __syncthreads();
      if (tid==0){
        u64 bb2 = sh_arg[0];
        for (int w=1;w<8;++w) if (sh_arg[w] > bb2) bb2 = sh_arg[w];
        stA8(argp + b, bb2);
      }
    }
    GSYNC();
  }
  // ================= final word =================
  if (b==0) {
    if (tid < NB_) {
      u64 v = ldA8(argp + tid);
      v = wmax64(v);
      if (lane==0) sh_arg[wave] = v;
    }
    __syncthreads();
    if (tid==0){
      u64 best = sh_arg[0];
      for (int w=1;w<4;++w) if (sh_arg[w]>best) best = sh_arg[w];
      out[S_] = (float)(0xFFFFFFFFu - (u32)best);
    }
  }
}

extern "C" void kernel_launch(void* const* d_in, const int* in_sizes, int n_in,
                              void* d_out, int out_size, void* d_ws, size_t ws_size,
                              hipStream_t stream) {
  (void)in_sizes; (void)n_in; (void)out_size; (void)ws_size;
  hipMemsetAsync(d_ws, 0, 20480, stream);   // genArr + flags + argp
  hipLaunchKernelGGL(seq2seq_kernel, dim3(NB_), dim3(NT_), 0, stream,
    (const int*)  d_in[0],
    (const float*)d_in[2],  (const float*)d_in[3],
    (const float*)d_in[4],  (const float*)d_in[5],  (const float*)d_in[6],
    (const float*)d_in[7],  (const float*)d_in[8],  (const float*)d_in[9],
    (const float*)d_in[10], (const float*)d_in[11], (const float*)d_in[12],
    (const float*)d_in[13], (const float*)d_in[14],
    (const float*)d_in[15], (const float*)d_in[16],
    (const float*)d_in[17], (const float*)d_in[18],
    (float*)d_out, (char*)d_ws);
}